// Round 1
// baseline (2549.979 us; speedup 1.0000x reference)
//
#include <hip/hip_runtime.h>
#include <hip/hip_fp16.h>

// Problem constants
constexpr int B_  = 8;
constexpr int H_  = 64;
constexpr int W_  = 64;
constexpr int C_  = 256;
constexpr int CG_ = 32;    // g/f output channels
constexpr int CH_ = 128;   // h output channels
constexpr int CO_ = 192;   // combined conv output channels (32 g + 32 f + 128 h)
constexpr int K9_ = 2304;  // 9 * 256 im2col depth
constexpr int NQ_ = 4096;  // H*W
constexpr int NM_ = 1024;  // (H/2)*(W/2)

// ---------------------------------------------------------------------------
// Prep: repack Wg/Wf/Wh (HWIO, [k][co]) into co-major Wc[192][2304]
// co 0..31 = g (Wg), 32..63 = f (Wf), 64..191 = h (Wh)
// ---------------------------------------------------------------------------
__global__ void prep_wc_k(const float* __restrict__ Wg, const float* __restrict__ Wf,
                          const float* __restrict__ Wh, float* __restrict__ Wc) {
    int i = blockIdx.x * 256 + threadIdx.x;
    if (i >= CO_ * K9_) return;
    int co = i / K9_;
    int k  = i - co * K9_;
    float v;
    if (co < 32)      v = Wg[k * 32  + co];
    else if (co < 64) v = Wf[k * 32  + (co - 32)];
    else              v = Wh[k * 128 + (co - 64)];
    Wc[i] = v;
}

// ---------------------------------------------------------------------------
// 3x3 SAME conv, all 192 output channels in one pass.
// Block = one (b, y) row. 512 threads: x = tid&63, cq = tid>>6 (8 groups of 24 co).
// Weight loads are wave-uniform (same cq per wave) -> broadcast from L1/L2.
// ---------------------------------------------------------------------------
__global__ __launch_bounds__(512) void conv3x3_k(
        const float* __restrict__ X, const float* __restrict__ Wc,
        const float* __restrict__ bg, const float* __restrict__ bf, const float* __restrict__ bh,
        float* __restrict__ g, float* __restrict__ fpre, float* __restrict__ hpre) {
    int b  = blockIdx.x >> 6;
    int y  = blockIdx.x & 63;
    int x  = threadIdx.x & 63;
    int cq = threadIdx.x >> 6;          // 0..7

    float acc[24];
#pragma unroll
    for (int j = 0; j < 24; ++j) acc[j] = 0.f;

    const float* wq = Wc + (size_t)(cq * 24) * K9_;

    for (int ky = 0; ky < 3; ++ky) {
        int yy = y + ky - 1;
        if (yy < 0 || yy >= H_) continue;
        const float* xrow = X + ((size_t)(b * H_ + yy) * W_) * C_;
        for (int kx = 0; kx < 3; ++kx) {
            int xx = x + kx - 1;
            if (xx < 0 || xx >= W_) continue;      // only border lanes diverge
            const float4* xp = reinterpret_cast<const float4*>(xrow + (size_t)xx * C_);
            const float* wk = wq + (ky * 3 + kx) * C_;
            for (int c4 = 0; c4 < 64; ++c4) {
                float4 xv = xp[c4];
#pragma unroll
                for (int j = 0; j < 24; ++j) {
                    float4 wv = *reinterpret_cast<const float4*>(wk + (size_t)j * K9_ + c4 * 4);
                    acc[j] = fmaf(xv.x, wv.x, acc[j]);
                    acc[j] = fmaf(xv.y, wv.y, acc[j]);
                    acc[j] = fmaf(xv.z, wv.z, acc[j]);
                    acc[j] = fmaf(xv.w, wv.w, acc[j]);
                }
            }
        }
    }

    int pix = (b * H_ + y) * W_ + x;
#pragma unroll
    for (int j = 0; j < 24; ++j) {
        int co = cq * 24 + j;                      // uniform across lanes
        float v = acc[j];
        if (co < 32)        g[(size_t)pix * 32  + co]        = v + bg[co];
        else if (co < 64)   fpre[(size_t)pix * 32  + (co-32)] = v + bf[co - 32];
        else                hpre[(size_t)pix * 128 + (co-64)] = v + bh[co - 64];
    }
}

// ---------------------------------------------------------------------------
// 2x2 maxpool stride 2 (64x64 -> 32x32), channels-last
// ---------------------------------------------------------------------------
__global__ void maxpool_k(const float* __restrict__ src, float* __restrict__ dst,
                          int Cc, int total) {
    int i = blockIdx.x * 256 + threadIdx.x;
    if (i >= total) return;
    int c = i % Cc;
    int t = i / Cc;
    int px = t & 31; t >>= 5;
    int py = t & 31;
    int b  = t >> 5;
    const float* s = src + (((size_t)(b * 64 + py * 2)) * 64 + px * 2) * Cc + c;
    float v = fmaxf(fmaxf(s[0], s[Cc]), fmaxf(s[64 * Cc], s[64 * Cc + Cc]));
    dst[i] = v;
}

// ---------------------------------------------------------------------------
// Attention: per block, 16 query rows. Logits & P stored as f16 in LDS
// (f32 would exceed 64KB static LDS; f16 keeps error well under threshold).
// ---------------------------------------------------------------------------
constexpr int QT_ = 16;
constexpr int SP_ = 1040;   // f16 row pitch (pad to de-conflict banks)

__global__ __launch_bounds__(256) void attn_k(
        const float* __restrict__ Qg,   // [B, 4096, 32]
        const float* __restrict__ Kf,   // [B, 1024, 32]
        const float* __restrict__ Vh,   // [B, 1024, 128]
        float* __restrict__ wo) {       // [B, 4096, 128]
    __shared__ __half S[QT_ * SP_];     // 33.3 KB
    __shared__ float  Qs[QT_][32];
    __shared__ float  invsum[QT_];

    int blk = blockIdx.x;
    int bb  = blk >> 8;                 // 256 q-tiles per batch
    int qt  = blk & 255;
    int r0  = qt * QT_;
    int tid = threadIdx.x;

    // load Q tile
    for (int idx = tid; idx < QT_ * 32; idx += 256) {
        int r = idx >> 5, d = idx & 31;
        Qs[r][d] = Qg[((size_t)bb * NQ_ + r0 + r) * 32 + d];
    }
    __syncthreads();

    // S = Q K^T  (logits, f16)
    for (int idx = tid; idx < QT_ * NM_; idx += 256) {
        int r = idx >> 10, m = idx & 1023;
        const float4* kp = reinterpret_cast<const float4*>(Kf + ((size_t)bb * NM_ + m) * CG_);
        const float4* qp = reinterpret_cast<const float4*>(Qs[r]);
        float acc = 0.f;
#pragma unroll
        for (int i = 0; i < 8; ++i) {
            float4 kv = kp[i], qv = qp[i];
            acc = fmaf(kv.x, qv.x, acc);
            acc = fmaf(kv.y, qv.y, acc);
            acc = fmaf(kv.z, qv.z, acc);
            acc = fmaf(kv.w, qv.w, acc);
        }
        S[r * SP_ + m] = __float2half(acc);
    }
    __syncthreads();

    // softmax: 16 threads per row
    {
        int r  = tid >> 4;
        int tg = tid & 15;
        int base = r * SP_;
        float lmax = -3.0e38f;
        for (int j = 0; j < 64; ++j)
            lmax = fmaxf(lmax, __half2float(S[base + tg + j * 16]));
#pragma unroll
        for (int off = 1; off < 16; off <<= 1)
            lmax = fmaxf(lmax, __shfl_xor(lmax, off, 64));
        float lsum = 0.f;
        for (int j = 0; j < 64; ++j) {
            int idx = base + tg + j * 16;
            float e = __expf(__half2float(S[idx]) - lmax);
            lsum += e;
            S[idx] = __float2half(e);
        }
#pragma unroll
        for (int off = 1; off < 16; off <<= 1)
            lsum += __shfl_xor(lsum, off, 64);
        if (tg == 0) invsum[r] = 1.f / lsum;
    }
    __syncthreads();

    // O = P V : thread handles 2 rows x 4 v-columns (float4)
    {
        int v4 = tid & 31;              // column group (v = v4*4..v4*4+3)
        int rg = tid >> 5;              // 0..7
        int ra = rg * 2, rb = ra + 1;
        float4 a0 = {0, 0, 0, 0}, a1 = {0, 0, 0, 0};
        const float4* vp = reinterpret_cast<const float4*>(Vh + (size_t)bb * NM_ * CH_) + v4;
        for (int m = 0; m < NM_; ++m) {
            float4 vv = vp[(size_t)m * 32];
            float w0 = __half2float(S[ra * SP_ + m]);
            float w1 = __half2float(S[rb * SP_ + m]);
            a0.x = fmaf(w0, vv.x, a0.x); a0.y = fmaf(w0, vv.y, a0.y);
            a0.z = fmaf(w0, vv.z, a0.z); a0.w = fmaf(w0, vv.w, a0.w);
            a1.x = fmaf(w1, vv.x, a1.x); a1.y = fmaf(w1, vv.y, a1.y);
            a1.z = fmaf(w1, vv.z, a1.z); a1.w = fmaf(w1, vv.w, a1.w);
        }
        float s0 = invsum[ra], s1 = invsum[rb];
        float4* o0 = reinterpret_cast<float4*>(wo + ((size_t)bb * NQ_ + r0 + ra) * CH_) + v4;
        float4* o1 = reinterpret_cast<float4*>(wo + ((size_t)bb * NQ_ + r0 + rb) * CH_) + v4;
        *o0 = make_float4(a0.x * s0, a0.y * s0, a0.z * s0, a0.w * s0);
        *o1 = make_float4(a1.x * s1, a1.y * s1, a1.z * s1, a1.w * s1);
    }
}

// ---------------------------------------------------------------------------
// 1x1 conv (128->256) + bias + gated residual.
// Block = 16 rows; thread c computes 16 outputs; Wo reads coalesced.
// ---------------------------------------------------------------------------
__global__ __launch_bounds__(256) void conv1x1_res_k(
        const float* __restrict__ wo, const float* __restrict__ Wo,
        const float* __restrict__ bo, const float* __restrict__ X,
        const float* __restrict__ gate, float* __restrict__ out) {
    __shared__ float ws_[16][128];
    int rowbase = blockIdx.x * 16;
    int tid = threadIdx.x;
    for (int idx = tid; idx < 16 * 128; idx += 256) {
        int r = idx >> 7, v = idx & 127;
        ws_[r][v] = wo[(size_t)(rowbase + r) * 128 + v];
    }
    __syncthreads();
    int c = tid;   // 0..255
    float acc[16];
#pragma unroll
    for (int r = 0; r < 16; ++r) acc[r] = 0.f;
    for (int v = 0; v < 128; ++v) {
        float wv = Wo[(size_t)v * 256 + c];
#pragma unroll
        for (int r = 0; r < 16; ++r) acc[r] = fmaf(ws_[r][v], wv, acc[r]);
    }
    float gt = gate[0];
    float bc = bo[c];
#pragma unroll
    for (int r = 0; r < 16; ++r) {
        size_t o = (size_t)(rowbase + r) * 256 + c;
        out[o] = X[o] + gt * (acc[r] + bc);
    }
}

// ---------------------------------------------------------------------------
extern "C" void kernel_launch(void* const* d_in, const int* in_sizes, int n_in,
                              void* d_out, int out_size, void* d_ws, size_t ws_size,
                              hipStream_t stream) {
    const float* X    = (const float*)d_in[0];
    const float* Wf   = (const float*)d_in[1];
    const float* bf   = (const float*)d_in[2];
    const float* Wg   = (const float*)d_in[3];
    const float* bg   = (const float*)d_in[4];
    const float* Wh   = (const float*)d_in[5];
    const float* bh   = (const float*)d_in[6];
    const float* Wo   = (const float*)d_in[7];
    const float* bo   = (const float*)d_in[8];
    const float* gate = (const float*)d_in[9];
    float* out = (float*)d_out;

    // workspace layout (floats) — total ~32.2 MB
    float* ws   = (float*)d_ws;
    float* Wc   = ws;                       // 192*2304   = 442368
    float* gbuf = Wc   + 442368;            // 8*4096*32  = 1048576
    float* fpre = gbuf + 1048576;           // 8*4096*32  = 1048576
    float* hpre = fpre + 1048576;           // 8*4096*128 = 4194304
    float* fbuf = hpre + 4194304;           // 8*1024*32  = 262144
    float* hbuf = fbuf + 262144;            // 8*1024*128 = 1048576
    float* wobuf = hpre;                    // alias: hpre dead after pooling

    // 1) weight repack
    prep_wc_k<<<(CO_ * K9_ + 255) / 256, 256, 0, stream>>>(Wg, Wf, Wh, Wc);
    // 2) fused 3x3 convs (g, f-pre, h-pre)
    conv3x3_k<<<B_ * H_, 512, 0, stream>>>(X, Wc, bg, bf, bh, gbuf, fpre, hpre);
    // 3) maxpools
    maxpool_k<<<(B_ * 1024 * CG_ + 255) / 256, 256, 0, stream>>>(fpre, fbuf, CG_, B_ * 1024 * CG_);
    maxpool_k<<<(B_ * 1024 * CH_ + 255) / 256, 256, 0, stream>>>(hpre, hbuf, CH_, B_ * 1024 * CH_);
    // 4) attention (writes wobuf, aliasing hpre which is now dead)
    attn_k<<<B_ * (NQ_ / QT_), 256, 0, stream>>>(gbuf, fbuf, hbuf, wobuf);
    // 5) 1x1 conv + residual
    conv1x1_res_k<<<(B_ * NQ_) / 16, 256, 0, stream>>>(wobuf, Wo, bo, X, gate, out);
}

// Round 3
// 784.724 us; speedup vs baseline: 3.2495x; 3.2495x over previous
//
#include <hip/hip_runtime.h>
#include <hip/hip_fp16.h>

// Problem constants
constexpr int B_  = 8;
constexpr int H_  = 64;
constexpr int W_  = 64;
constexpr int C_  = 256;
constexpr int CG_ = 32;    // g/f output channels
constexpr int CH_ = 128;   // h output channels
constexpr int NQ_ = 4096;  // H*W
constexpr int NM_ = 1024;  // (H/2)*(W/2)
constexpr int XP_ = 66;    // padded spatial dim

typedef __attribute__((ext_vector_type(8))) _Float16 half8;
typedef __attribute__((ext_vector_type(4))) float    f32x4;

// ---------------------------------------------------------------------------
// Prep: X f32 [8,64,64,256] -> Xpad f16 [8][66][66][256] with zero border.
// One thread per 8-element chunk.
// ---------------------------------------------------------------------------
__global__ void prep_xpad_k(const float* __restrict__ X, _Float16* __restrict__ Xpad) {
    int i8 = blockIdx.x * 256 + threadIdx.x;
    if (i8 >= B_ * XP_ * XP_ * 32) return;
    int c8 = i8 & 31;          // which 8-chunk of 256 channels
    int px = i8 >> 5;
    int xx = px % XP_;
    int t  = px / XP_;
    int yy = t % XP_;
    int b  = t / XP_;
    half8 v;
    if (yy >= 1 && yy <= 64 && xx >= 1 && xx <= 64) {
        const float* s = X + (((size_t)(b * 64 + yy - 1) * 64) + (xx - 1)) * 256 + c8 * 8;
        float4 a = *reinterpret_cast<const float4*>(s);
        float4 bv = *reinterpret_cast<const float4*>(s + 4);
        v[0] = (_Float16)a.x;  v[1] = (_Float16)a.y;
        v[2] = (_Float16)a.z;  v[3] = (_Float16)a.w;
        v[4] = (_Float16)bv.x; v[5] = (_Float16)bv.y;
        v[6] = (_Float16)bv.z; v[7] = (_Float16)bv.w;
    } else {
        v = (half8)(_Float16)0.f;
    }
    *reinterpret_cast<half8*>(Xpad + (size_t)i8 * 8) = v;
}

// ---------------------------------------------------------------------------
// Prep: pack Wg/Wf/Wh (HWIO [k][co]) into MFMA-fragment-major f16:
// Wpk[co16][tap][ks][lane][8]; co16 = co/16 (0..11: 0-1 g, 2-3 f, 4-11 h)
// lane l holds B[k = (l>>4)*8 + j][col = l&15] for the 32-k step.
// ---------------------------------------------------------------------------
__global__ void prep_wpk_k(const float* __restrict__ Wg, const float* __restrict__ Wf,
                           const float* __restrict__ Wh, _Float16* __restrict__ Wpk) {
    int i = blockIdx.x * 256 + threadIdx.x;
    if (i >= 12 * 9 * 8 * 64 * 8) return;
    int j    = i & 7;
    int lane = (i >> 3) & 63;
    int ks   = (i >> 9) & 7;
    int tap  = (i >> 12) % 9;
    int co16 = i / 36864;
    int lr = lane & 15, lk = lane >> 4;
    int co = co16 * 16 + lr;
    int kk = tap * 256 + ks * 32 + lk * 8 + j;
    float v;
    if (co < 32)      v = Wg[(size_t)kk * 32  + co];
    else if (co < 64) v = Wf[(size_t)kk * 32  + (co - 32)];
    else              v = Wh[(size_t)kk * 128 + (co - 64)];
    Wpk[i] = (_Float16)v;
}

__global__ void prep_bias_k(const float* __restrict__ bg, const float* __restrict__ bf,
                            const float* __restrict__ bh, float* __restrict__ bc) {
    int co = threadIdx.x;
    if (co >= 192) return;
    bc[co] = (co < 32) ? bg[co] : (co < 64) ? bf[co - 32] : bh[co - 64];
}

// ---------------------------------------------------------------------------
// Fused 3x3 convs as implicit GEMM via f16 MFMA.
// Block = one output row (b, y): M=64 pixels, N=192 co, K=9*256.
// 4 waves split N (48 co each). LDS stages one padded input row per ky
// (66 px * 256 ch f16 = 33 KB) with XOR swizzle to kill bank conflicts.
// ---------------------------------------------------------------------------
__global__ __launch_bounds__(256) void conv_mfma_k(
        const _Float16* __restrict__ Xpad, const _Float16* __restrict__ Wpk,
        const float* __restrict__ bc,
        float* __restrict__ g, float* __restrict__ fpre, float* __restrict__ hpre) {
    __shared__ char lds[XP_ * 256 * 2];   // 33792 B
    int b   = blockIdx.x >> 6;
    int y   = blockIdx.x & 63;
    int tid = threadIdx.x;
    int wid = tid >> 6;        // 0..3 : co block wid*48
    int l   = tid & 63;
    int lr  = l & 15;
    int lk  = l >> 4;

    f32x4 acc[4][3];
#pragma unroll
    for (int mi = 0; mi < 4; ++mi)
#pragma unroll
        for (int nj = 0; nj < 3; ++nj) acc[mi][nj] = (f32x4)0.f;

    for (int ky = 0; ky < 3; ++ky) {
        __syncthreads();
        // stage padded row (b, y+ky): 2112 16-byte chunks, swizzled
        const _Float16* src = Xpad + ((size_t)(b * XP_ + y + ky) * XP_) * 256;
        for (int c16 = tid; c16 < XP_ * 32; c16 += 256) {
            float4 v = reinterpret_cast<const float4*>(src)[c16];
            int a  = c16 * 16;
            int px = c16 >> 5;
            *reinterpret_cast<float4*>(lds + (a ^ ((px & 7) << 4))) = v;
        }
        __syncthreads();

        for (int kx = 0; kx < 3; ++kx) {
            int tap = ky * 3 + kx;
#pragma unroll
            for (int ks = 0; ks < 8; ++ks) {
                half8 af[4];
#pragma unroll
                for (int mi = 0; mi < 4; ++mi) {
                    int px = mi * 16 + lr + kx;
                    int ad = (px * 512 + ks * 64 + lk * 16) ^ ((px & 7) << 4);
                    af[mi] = *reinterpret_cast<const half8*>(lds + ad);
                }
#pragma unroll
                for (int nj = 0; nj < 3; ++nj) {
                    int co16 = wid * 3 + nj;
                    half8 bf8 = *reinterpret_cast<const half8*>(
                        Wpk + ((((size_t)co16 * 9 + tap) * 8 + ks) * 64 + l) * 8);
#pragma unroll
                    for (int mi = 0; mi < 4; ++mi)
                        acc[mi][nj] = __builtin_amdgcn_mfma_f32_16x16x32_f16(
                            af[mi], bf8, acc[mi][nj], 0, 0, 0);
                }
            }
        }
    }

    // epilogue: D layout col=lane&15 (co), row=(lane>>4)*4+reg (pixel x)
    int pixbase = (b * 64 + y) * 64;
#pragma unroll
    for (int nj = 0; nj < 3; ++nj) {
        int co = wid * 48 + nj * 16 + lr;
        float bias = bc[co];
#pragma unroll
        for (int mi = 0; mi < 4; ++mi) {
#pragma unroll
            for (int r = 0; r < 4; ++r) {
                int x = mi * 16 + lk * 4 + r;
                float v = acc[mi][nj][r] + bias;
                size_t pix = pixbase + x;
                if (co < 32)        g[pix * 32  + co]          = v;
                else if (co < 64)   fpre[pix * 32  + (co - 32)] = v;
                else                hpre[pix * 128 + (co - 64)] = v;
            }
        }
    }
}

// ---------------------------------------------------------------------------
// 2x2 maxpool stride 2 (64x64 -> 32x32), channels-last
// ---------------------------------------------------------------------------
__global__ void maxpool_k(const float* __restrict__ src, float* __restrict__ dst,
                          int Cc, int total) {
    int i = blockIdx.x * 256 + threadIdx.x;
    if (i >= total) return;
    int c = i % Cc;
    int t = i / Cc;
    int px = t & 31; t >>= 5;
    int py = t & 31;
    int b  = t >> 5;
    const float* s = src + (((size_t)(b * 64 + py * 2)) * 64 + px * 2) * Cc + c;
    float v = fmaxf(fmaxf(s[0], s[Cc]), fmaxf(s[64 * Cc], s[64 * Cc + Cc]));
    dst[i] = v;
}

// ---------------------------------------------------------------------------
// Attention: per block, 16 query rows. Logits & P stored as f16 in LDS.
// ---------------------------------------------------------------------------
constexpr int QT_ = 16;
constexpr int SP_ = 1040;   // f16 row pitch (pad to de-conflict banks)

__global__ __launch_bounds__(256) void attn_k(
        const float* __restrict__ Qg,   // [B, 4096, 32]
        const float* __restrict__ Kf,   // [B, 1024, 32]
        const float* __restrict__ Vh,   // [B, 1024, 128]
        float* __restrict__ wo) {       // [B, 4096, 128]
    __shared__ __half S[QT_ * SP_];     // 33.3 KB
    __shared__ float  Qs[QT_][32];
    __shared__ float  invsum[QT_];

    int blk = blockIdx.x;
    int bb  = blk >> 8;
    int qt  = blk & 255;
    int r0  = qt * QT_;
    int tid = threadIdx.x;

    for (int idx = tid; idx < QT_ * 32; idx += 256) {
        int r = idx >> 5, d = idx & 31;
        Qs[r][d] = Qg[((size_t)bb * NQ_ + r0 + r) * 32 + d];
    }
    __syncthreads();

    for (int idx = tid; idx < QT_ * NM_; idx += 256) {
        int r = idx >> 10, m = idx & 1023;
        const float4* kp = reinterpret_cast<const float4*>(Kf + ((size_t)bb * NM_ + m) * CG_);
        const float4* qp = reinterpret_cast<const float4*>(Qs[r]);
        float acc = 0.f;
#pragma unroll
        for (int i = 0; i < 8; ++i) {
            float4 kv = kp[i], qv = qp[i];
            acc = fmaf(kv.x, qv.x, acc);
            acc = fmaf(kv.y, qv.y, acc);
            acc = fmaf(kv.z, qv.z, acc);
            acc = fmaf(kv.w, qv.w, acc);
        }
        S[r * SP_ + m] = __float2half(acc);
    }
    __syncthreads();

    {
        int r  = tid >> 4;
        int tg = tid & 15;
        int base = r * SP_;
        float lmax = -3.0e38f;
        for (int j = 0; j < 64; ++j)
            lmax = fmaxf(lmax, __half2float(S[base + tg + j * 16]));
#pragma unroll
        for (int off = 1; off < 16; off <<= 1)
            lmax = fmaxf(lmax, __shfl_xor(lmax, off, 64));
        float lsum = 0.f;
        for (int j = 0; j < 64; ++j) {
            int idx = base + tg + j * 16;
            float e = __expf(__half2float(S[idx]) - lmax);
            lsum += e;
            S[idx] = __float2half(e);
        }
#pragma unroll
        for (int off = 1; off < 16; off <<= 1)
            lsum += __shfl_xor(lsum, off, 64);
        if (tg == 0) invsum[r] = 1.f / lsum;
    }
    __syncthreads();

    {
        int v4 = tid & 31;
        int rg = tid >> 5;
        int ra = rg * 2, rb = ra + 1;
        float4 a0 = {0, 0, 0, 0}, a1 = {0, 0, 0, 0};
        const float4* vp = reinterpret_cast<const float4*>(Vh + (size_t)bb * NM_ * CH_) + v4;
        for (int m = 0; m < NM_; ++m) {
            float4 vv = vp[(size_t)m * 32];
            float w0 = __half2float(S[ra * SP_ + m]);
            float w1 = __half2float(S[rb * SP_ + m]);
            a0.x = fmaf(w0, vv.x, a0.x); a0.y = fmaf(w0, vv.y, a0.y);
            a0.z = fmaf(w0, vv.z, a0.z); a0.w = fmaf(w0, vv.w, a0.w);
            a1.x = fmaf(w1, vv.x, a1.x); a1.y = fmaf(w1, vv.y, a1.y);
            a1.z = fmaf(w1, vv.z, a1.z); a1.w = fmaf(w1, vv.w, a1.w);
        }
        float s0 = invsum[ra], s1 = invsum[rb];
        float4* o0 = reinterpret_cast<float4*>(wo + ((size_t)bb * NQ_ + r0 + ra) * CH_) + v4;
        float4* o1 = reinterpret_cast<float4*>(wo + ((size_t)bb * NQ_ + r0 + rb) * CH_) + v4;
        *o0 = make_float4(a0.x * s0, a0.y * s0, a0.z * s0, a0.w * s0);
        *o1 = make_float4(a1.x * s1, a1.y * s1, a1.z * s1, a1.w * s1);
    }
}

// ---------------------------------------------------------------------------
// 1x1 conv (128->256) + bias + gated residual.
// ---------------------------------------------------------------------------
__global__ __launch_bounds__(256) void conv1x1_res_k(
        const float* __restrict__ wo, const float* __restrict__ Wo,
        const float* __restrict__ bo, const float* __restrict__ X,
        const float* __restrict__ gate, float* __restrict__ out) {
    __shared__ float ws_[16][128];
    int rowbase = blockIdx.x * 16;
    int tid = threadIdx.x;
    for (int idx = tid; idx < 16 * 128; idx += 256) {
        int r = idx >> 7, v = idx & 127;
        ws_[r][v] = wo[(size_t)(rowbase + r) * 128 + v];
    }
    __syncthreads();
    int c = tid;
    float acc[16];
#pragma unroll
    for (int r = 0; r < 16; ++r) acc[r] = 0.f;
    for (int v = 0; v < 128; ++v) {
        float wv = Wo[(size_t)v * 256 + c];
#pragma unroll
        for (int r = 0; r < 16; ++r) acc[r] = fmaf(ws_[r][v], wv, acc[r]);
    }
    float gt = gate[0];
    float bc = bo[c];
#pragma unroll
    for (int r = 0; r < 16; ++r) {
        size_t o = (size_t)(rowbase + r) * 256 + c;
        out[o] = X[o] + gt * (acc[r] + bc);
    }
}

// ---------------------------------------------------------------------------
extern "C" void kernel_launch(void* const* d_in, const int* in_sizes, int n_in,
                              void* d_out, int out_size, void* d_ws, size_t ws_size,
                              hipStream_t stream) {
    const float* X    = (const float*)d_in[0];
    const float* Wf   = (const float*)d_in[1];
    const float* bf   = (const float*)d_in[2];
    const float* Wg   = (const float*)d_in[3];
    const float* bg   = (const float*)d_in[4];
    const float* Wh   = (const float*)d_in[5];
    const float* bh   = (const float*)d_in[6];
    const float* Wo   = (const float*)d_in[7];
    const float* bo   = (const float*)d_in[8];
    const float* gate = (const float*)d_in[9];
    float* out = (float*)d_out;

    // workspace layout (in floats) — ~49 MB total
    float* ws   = (float*)d_ws;
    float* gbuf = ws;                        // 8*4096*32  = 1048576
    float* fpre = gbuf + 1048576;            // 8*4096*32  = 1048576
    float* hpre = fpre + 1048576;            // 8*4096*128 = 4194304
    float* fbuf = hpre + 4194304;            // 8*1024*32  = 262144
    float* hbuf = fbuf + 262144;             // 8*1024*128 = 1048576
    _Float16* Xpad = (_Float16*)(hbuf + 1048576);   // 8*66*66*256 f16 = 4460544 floats
    _Float16* Wpk  = (_Float16*)((float*)Xpad + 4460544); // 442368 f16 = 221184 floats
    float* bc   = (float*)Wpk + 221184;      // 192
    float* wobuf = hpre;                     // alias: hpre dead after pooling

    // 1) preps
    prep_xpad_k<<<(B_ * XP_ * XP_ * 32 + 255) / 256, 256, 0, stream>>>(X, Xpad);
    prep_wpk_k<<<(12 * 9 * 8 * 64 * 8 + 255) / 256, 256, 0, stream>>>(Wg, Wf, Wh, Wpk);
    prep_bias_k<<<1, 256, 0, stream>>>(bg, bf, bh, bc);
    // 2) fused 3x3 convs via MFMA
    conv_mfma_k<<<B_ * H_, 256, 0, stream>>>(Xpad, Wpk, bc, gbuf, fpre, hpre);
    // 3) maxpools
    maxpool_k<<<(B_ * 1024 * CG_ + 255) / 256, 256, 0, stream>>>(fpre, fbuf, CG_, B_ * 1024 * CG_);
    maxpool_k<<<(B_ * 1024 * CH_ + 255) / 256, 256, 0, stream>>>(hpre, hbuf, CH_, B_ * 1024 * CH_);
    // 4) attention
    attn_k<<<B_ * (NQ_ / QT_), 256, 0, stream>>>(gbuf, fbuf, hbuf, wobuf);
    // 5) 1x1 conv + residual
    conv1x1_res_k<<<(B_ * NQ_) / 16, 256, 0, stream>>>(wobuf, Wo, bo, X, gate, out);
}

// Round 4
// 183.396 us; speedup vs baseline: 13.9042x; 4.2789x over previous
//
#include <hip/hip_runtime.h>
#include <hip/hip_fp16.h>

// Problem constants
constexpr int B_  = 8;
constexpr int H_  = 64;
constexpr int W_  = 64;
constexpr int C_  = 256;
constexpr int CG_ = 32;    // g/f output channels
constexpr int CH_ = 128;   // h output channels
constexpr int NQ_ = 4096;  // H*W
constexpr int NM_ = 1024;  // (H/2)*(W/2)
constexpr int XP_ = 66;    // padded spatial dim

typedef __attribute__((ext_vector_type(8))) _Float16 half8;
typedef __attribute__((ext_vector_type(4))) _Float16 half4;
typedef __attribute__((ext_vector_type(4))) float    f32x4;

// ---------------------------------------------------------------------------
// Prep: X f32 -> Xpad f16 [8][66][66][256], zero border.
// ---------------------------------------------------------------------------
__global__ void prep_xpad_k(const float* __restrict__ X, _Float16* __restrict__ Xpad) {
    int i8 = blockIdx.x * 256 + threadIdx.x;
    if (i8 >= B_ * XP_ * XP_ * 32) return;
    int c8 = i8 & 31;
    int px = i8 >> 5;
    int xx = px % XP_;
    int t  = px / XP_;
    int yy = t % XP_;
    int b  = t / XP_;
    half8 v;
    if (yy >= 1 && yy <= 64 && xx >= 1 && xx <= 64) {
        const float* s = X + (((size_t)(b * 64 + yy - 1) * 64) + (xx - 1)) * 256 + c8 * 8;
        float4 a = *reinterpret_cast<const float4*>(s);
        float4 bv = *reinterpret_cast<const float4*>(s + 4);
        v[0] = (_Float16)a.x;  v[1] = (_Float16)a.y;
        v[2] = (_Float16)a.z;  v[3] = (_Float16)a.w;
        v[4] = (_Float16)bv.x; v[5] = (_Float16)bv.y;
        v[6] = (_Float16)bv.z; v[7] = (_Float16)bv.w;
    } else {
        v = (half8)(_Float16)0.f;
    }
    *reinterpret_cast<half8*>(Xpad + (size_t)i8 * 8) = v;
}

// ---------------------------------------------------------------------------
// Prep: pack Wg/Wf/Wh into MFMA-fragment-major f16 (B-fragment layout).
// ---------------------------------------------------------------------------
__global__ void prep_wpk_k(const float* __restrict__ Wg, const float* __restrict__ Wf,
                           const float* __restrict__ Wh, _Float16* __restrict__ Wpk) {
    int i = blockIdx.x * 256 + threadIdx.x;
    if (i >= 12 * 9 * 8 * 64 * 8) return;
    int j    = i & 7;
    int lane = (i >> 3) & 63;
    int ks   = (i >> 9) & 7;
    int tap  = (i >> 12) % 9;
    int co16 = i / 36864;
    int lr = lane & 15, lk = lane >> 4;
    int co = co16 * 16 + lr;
    int kk = tap * 256 + ks * 32 + lk * 8 + j;
    float v;
    if (co < 32)      v = Wg[(size_t)kk * 32  + co];
    else if (co < 64) v = Wf[(size_t)kk * 32  + (co - 32)];
    else              v = Wh[(size_t)kk * 128 + (co - 64)];
    Wpk[i] = (_Float16)v;
}

__global__ void prep_bias_k(const float* __restrict__ bg, const float* __restrict__ bf,
                            const float* __restrict__ bh, float* __restrict__ bc) {
    int co = threadIdx.x;
    if (co >= 192) return;
    bc[co] = (co < 32) ? bg[co] : (co < 64) ? bf[co - 32] : bh[co - 64];
}

// ---------------------------------------------------------------------------
// Fused 3x3 convs via f16 MFMA. Q (g path) written directly as f16.
// ---------------------------------------------------------------------------
__global__ __launch_bounds__(256) void conv_mfma_k(
        const _Float16* __restrict__ Xpad, const _Float16* __restrict__ Wpk,
        const float* __restrict__ bc,
        _Float16* __restrict__ gq, float* __restrict__ fpre, float* __restrict__ hpre) {
    __shared__ char lds[XP_ * 256 * 2];   // 33792 B
    int b   = blockIdx.x >> 6;
    int y   = blockIdx.x & 63;
    int tid = threadIdx.x;
    int wid = tid >> 6;
    int l   = tid & 63;
    int lr  = l & 15;
    int lk  = l >> 4;

    f32x4 acc[4][3];
#pragma unroll
    for (int mi = 0; mi < 4; ++mi)
#pragma unroll
        for (int nj = 0; nj < 3; ++nj) acc[mi][nj] = (f32x4)0.f;

    for (int ky = 0; ky < 3; ++ky) {
        __syncthreads();
        const _Float16* src = Xpad + ((size_t)(b * XP_ + y + ky) * XP_) * 256;
        for (int c16 = tid; c16 < XP_ * 32; c16 += 256) {
            float4 v = reinterpret_cast<const float4*>(src)[c16];
            int a  = c16 * 16;
            int px = c16 >> 5;
            *reinterpret_cast<float4*>(lds + (a ^ ((px & 7) << 4))) = v;
        }
        __syncthreads();

        for (int kx = 0; kx < 3; ++kx) {
            int tap = ky * 3 + kx;
#pragma unroll
            for (int ks = 0; ks < 8; ++ks) {
                half8 af[4];
#pragma unroll
                for (int mi = 0; mi < 4; ++mi) {
                    int px = mi * 16 + lr + kx;
                    int ad = (px * 512 + ks * 64 + lk * 16) ^ ((px & 7) << 4);
                    af[mi] = *reinterpret_cast<const half8*>(lds + ad);
                }
#pragma unroll
                for (int nj = 0; nj < 3; ++nj) {
                    int co16 = wid * 3 + nj;
                    half8 bf8 = *reinterpret_cast<const half8*>(
                        Wpk + ((((size_t)co16 * 9 + tap) * 8 + ks) * 64 + l) * 8);
#pragma unroll
                    for (int mi = 0; mi < 4; ++mi)
                        acc[mi][nj] = __builtin_amdgcn_mfma_f32_16x16x32_f16(
                            af[mi], bf8, acc[mi][nj], 0, 0, 0);
                }
            }
        }
    }

    int pixbase = (b * 64 + y) * 64;
#pragma unroll
    for (int nj = 0; nj < 3; ++nj) {
        int co = wid * 48 + nj * 16 + lr;
        float bias = bc[co];
#pragma unroll
        for (int mi = 0; mi < 4; ++mi) {
#pragma unroll
            for (int r = 0; r < 4; ++r) {
                int x = mi * 16 + lk * 4 + r;
                float v = acc[mi][nj][r] + bias;
                size_t pix = pixbase + x;
                if (co < 32)        gq[pix * 32  + co]          = (_Float16)v;
                else if (co < 64)   fpre[pix * 32  + (co - 32)] = v;
                else                hpre[pix * 128 + (co - 64)] = v;
            }
        }
    }
}

// ---------------------------------------------------------------------------
// 2x2 maxpool -> f16 keys K [B,1024,32]
// ---------------------------------------------------------------------------
__global__ void maxpool_f16_k(const float* __restrict__ src, _Float16* __restrict__ dst) {
    int i = blockIdx.x * 256 + threadIdx.x;
    if (i >= B_ * NM_ * CG_) return;
    int c = i & 31;
    int t = i >> 5;
    int px = t & 31;
    int py = (t >> 5) & 31;
    int b  = t >> 10;
    const float* s = src + (((size_t)(b * 64 + py * 2)) * 64 + px * 2) * 32 + c;
    float v = fmaxf(fmaxf(s[0], s[32]), fmaxf(s[64 * 32], s[64 * 32 + 32]));
    dst[i] = (_Float16)v;
}

// ---------------------------------------------------------------------------
// Fused 2x2 maxpool + transpose + f16: hpre [B,64,64,128] -> Vt [B][128][1024]
// ---------------------------------------------------------------------------
__global__ __launch_bounds__(256) void vtpool_k(const float* __restrict__ hpre,
                                                _Float16* __restrict__ Vt) {
    __shared__ float t[32][33];
    int b  = blockIdx.x >> 7;
    int kt = (blockIdx.x >> 2) & 31;   // pooled row (py); keys kt*32..kt*32+31
    int ct = blockIdx.x & 3;           // channel tile of 32
    int tid = threadIdx.x;
#pragma unroll
    for (int i = 0; i < 4; ++i) {
        int e = tid + i * 256;
        int px = e >> 5, c = e & 31;
        const float* s = hpre + (((size_t)(b * 64 + kt * 2) * 64) + px * 2) * 128 + ct * 32 + c;
        float v = fmaxf(fmaxf(s[0], s[128]), fmaxf(s[64 * 128], s[64 * 128 + 128]));
        t[px][c] = v;
    }
    __syncthreads();
#pragma unroll
    for (int i = 0; i < 4; ++i) {
        int e = tid + i * 256;
        int c = e >> 5, px = e & 31;
        Vt[((size_t)b * 128 + ct * 32 + c) * 1024 + kt * 32 + px] = (_Float16)t[px][c];
    }
}

// ---------------------------------------------------------------------------
// Flash attention via f16 MFMA.
// Block = 4 waves; wave owns 16 q-rows over all 1024 keys in 32-key steps.
// S^T = mfma(A=K, B=Q): lane's softmax state is for q = lane&15 (lane-local).
// P goes through a tiny padded LDS buffer to form the PV A-fragment.
// ---------------------------------------------------------------------------
constexpr int PP_ = 40;   // P_lds pitch in f16 (16B-aligned rows, conflict-free)

__global__ __launch_bounds__(256) void attn_flash_k(
        const _Float16* __restrict__ Qf,   // [B,4096,32]
        const _Float16* __restrict__ Kf,   // [B,1024,32]
        const _Float16* __restrict__ Vt,   // [B,128,1024]
        float* __restrict__ wo) {          // [B,4096,128]
    __shared__ _Float16 plds[4][16][PP_];  // 5120 B
    int bb  = blockIdx.x >> 6;
    int qt  = blockIdx.x & 63;
    int wid = threadIdx.x >> 6;
    int l   = threadIdx.x & 63;
    int lr  = l & 15;
    int lg  = l >> 4;
    int qbase = qt * 64 + wid * 16;

    // Q B-fragment (loaded once): lane holds Q[qbase+lr][lg*8+j]
    half8 bq = *reinterpret_cast<const half8*>(
        Qf + ((size_t)bb * NQ_ + qbase + lr) * 32 + lg * 8);

    const _Float16* Kb = Kf + (size_t)bb * NM_ * 32;
    const _Float16* Vb = Vt + (size_t)bb * 128 * NM_;

    f32x4 acc[8];
#pragma unroll
    for (int vt = 0; vt < 8; ++vt) acc[vt] = (f32x4)0.f;
    float m_run = -1.0e30f, l_run = 0.f;

    for (int kb = 0; kb < NM_; kb += 32) {
        // --- QK^T (S^T tiles) ---
        half8 ak0 = *reinterpret_cast<const half8*>(Kb + (size_t)(kb + lr) * 32 + lg * 8);
        half8 ak1 = *reinterpret_cast<const half8*>(Kb + (size_t)(kb + 16 + lr) * 32 + lg * 8);
        f32x4 s0 = __builtin_amdgcn_mfma_f32_16x16x32_f16(ak0, bq, (f32x4)0.f, 0, 0, 0);
        f32x4 s1 = __builtin_amdgcn_mfma_f32_16x16x32_f16(ak1, bq, (f32x4)0.f, 0, 0, 0);
        // lane holds S[q=qbase+lr][key=kb+4*lg+r] (s0) and kb+16+4*lg+r (s1)

        // tile max for this lane's q
        float tmax = fmaxf(fmaxf(fmaxf(s0[0], s0[1]), fmaxf(s0[2], s0[3])),
                           fmaxf(fmaxf(s1[0], s1[1]), fmaxf(s1[2], s1[3])));
        tmax = fmaxf(tmax, __shfl_xor(tmax, 16, 64));
        tmax = fmaxf(tmax, __shfl_xor(tmax, 32, 64));

        // deferred-max rescale
        if (__any(tmax > m_run + 8.f)) {
            float mnew  = fmaxf(m_run, tmax);
            float alpha = __expf(m_run - mnew);
            l_run *= alpha;
            m_run  = mnew;
#pragma unroll
            for (int r = 0; r < 4; ++r) {
                float ar = __shfl(alpha, 4 * lg + r, 64);
#pragma unroll
                for (int vt = 0; vt < 8; ++vt) acc[vt][r] *= ar;
            }
        }

        // p = exp(s - m_run), accumulate row sum
        float p0[4], p1[4];
        float psum = 0.f;
#pragma unroll
        for (int r = 0; r < 4; ++r) {
            p0[r] = __expf(s0[r] - m_run);
            p1[r] = __expf(s1[r] - m_run);
            psum += p0[r] + p1[r];
        }
        psum += __shfl_xor(psum, 16, 64);
        psum += __shfl_xor(psum, 32, 64);
        l_run += psum;

        // pack P to f16 and stage in LDS (wave-local; lgkmcnt orders it)
        half4 h0, h1;
#pragma unroll
        for (int r = 0; r < 4; ++r) { h0[r] = (_Float16)p0[r]; h1[r] = (_Float16)p1[r]; }
        *reinterpret_cast<half4*>(&plds[wid][lr][4 * lg])      = h0;
        *reinterpret_cast<half4*>(&plds[wid][lr][16 + 4 * lg]) = h1;

        // PV A-fragment: lane holds P[q=lr][key = kb + 8*lg + j]
        half8 ap = *reinterpret_cast<const half8*>(&plds[wid][lr][8 * lg]);

        // --- PV: 8 v-tiles of 16 cols ---
#pragma unroll
        for (int vt = 0; vt < 8; ++vt) {
            half8 bv = *reinterpret_cast<const half8*>(
                Vb + (size_t)(vt * 16 + lr) * NM_ + kb + 8 * lg);
            acc[vt] = __builtin_amdgcn_mfma_f32_16x16x32_f16(ap, bv, acc[vt], 0, 0, 0);
        }
    }

    // epilogue: normalize rows; acc row r is q = qbase + 4*lg + r
    float inv = 1.f / l_run;   // valid for q = qbase + lr
#pragma unroll
    for (int r = 0; r < 4; ++r) {
        float ir = __shfl(inv, 4 * lg + r, 64);
        float* orow = wo + ((size_t)bb * NQ_ + qbase + 4 * lg + r) * 128 + lr;
#pragma unroll
        for (int vt = 0; vt < 8; ++vt) orow[vt * 16] = acc[vt][r] * ir;
    }
}

// ---------------------------------------------------------------------------
// 1x1 conv (128->256) + bias + gated residual.
// ---------------------------------------------------------------------------
__global__ __launch_bounds__(256) void conv1x1_res_k(
        const float* __restrict__ wo, const float* __restrict__ Wo,
        const float* __restrict__ bo, const float* __restrict__ X,
        const float* __restrict__ gate, float* __restrict__ out) {
    __shared__ float ws_[16][128];
    int rowbase = blockIdx.x * 16;
    int tid = threadIdx.x;
    for (int idx = tid; idx < 16 * 128; idx += 256) {
        int r = idx >> 7, v = idx & 127;
        ws_[r][v] = wo[(size_t)(rowbase + r) * 128 + v];
    }
    __syncthreads();
    int c = tid;
    float acc[16];
#pragma unroll
    for (int r = 0; r < 16; ++r) acc[r] = 0.f;
    for (int v = 0; v < 128; ++v) {
        float wv = Wo[(size_t)v * 256 + c];
#pragma unroll
        for (int r = 0; r < 16; ++r) acc[r] = fmaf(ws_[r][v], wv, acc[r]);
    }
    float gt = gate[0];
    float bc = bo[c];
#pragma unroll
    for (int r = 0; r < 16; ++r) {
        size_t o = (size_t)(rowbase + r) * 256 + c;
        out[o] = X[o] + gt * (acc[r] + bc);
    }
}

// ---------------------------------------------------------------------------
extern "C" void kernel_launch(void* const* d_in, const int* in_sizes, int n_in,
                              void* d_out, int out_size, void* d_ws, size_t ws_size,
                              hipStream_t stream) {
    const float* X    = (const float*)d_in[0];
    const float* Wf   = (const float*)d_in[1];
    const float* bf   = (const float*)d_in[2];
    const float* Wg   = (const float*)d_in[3];
    const float* bg   = (const float*)d_in[4];
    const float* Wh   = (const float*)d_in[5];
    const float* bh   = (const float*)d_in[6];
    const float* Wo   = (const float*)d_in[7];
    const float* bo   = (const float*)d_in[8];
    const float* gate = (const float*)d_in[9];
    float* out = (float*)d_out;

    // workspace layout (float units) — ~45 MB total
    float* ws   = (float*)d_ws;
    float* fpre = ws;                          // 8*4096*32  f32 = 1048576
    float* hpre = fpre + 1048576;              // 8*4096*128 f32 = 4194304
    _Float16* gq = (_Float16*)(hpre + 4194304);   // 8*4096*32 f16  -> 524288 floats
    _Float16* Kf = (_Float16*)((float*)gq + 524288);  // 8*1024*32 f16 -> 131072 floats
    _Float16* Vt = (_Float16*)((float*)Kf + 131072);  // 8*128*1024 f16 -> 524288 floats
    _Float16* Xpad = (_Float16*)((float*)Vt + 524288);   // 8*66*66*256 f16 -> 4460544 floats
    _Float16* Wpk  = (_Float16*)((float*)Xpad + 4460544); // 442368 f16 -> 221184 floats
    float* bc   = (float*)Wpk + 221184;        // 192
    float* wobuf = hpre;                       // alias: hpre dead after vtpool

    // 1) preps
    prep_xpad_k<<<(B_ * XP_ * XP_ * 32 + 255) / 256, 256, 0, stream>>>(X, Xpad);
    prep_wpk_k<<<(12 * 9 * 8 * 64 * 8 + 255) / 256, 256, 0, stream>>>(Wg, Wf, Wh, Wpk);
    prep_bias_k<<<1, 256, 0, stream>>>(bg, bf, bh, bc);
    // 2) fused 3x3 convs via MFMA (Q written f16)
    conv_mfma_k<<<B_ * H_, 256, 0, stream>>>(Xpad, Wpk, bc, gq, fpre, hpre);
    // 3) pools: K f16, V pooled+transposed f16
    maxpool_f16_k<<<(B_ * NM_ * CG_ + 255) / 256, 256, 0, stream>>>(fpre, Kf);
    vtpool_k<<<B_ * 32 * 4, 256, 0, stream>>>(hpre, Vt);
    // 4) flash attention (MFMA)
    attn_flash_k<<<B_ * 64, 256, 0, stream>>>(gq, Kf, Vt, wobuf);
    // 5) 1x1 conv + residual
    conv1x1_res_k<<<(B_ * NQ_) / 16, 256, 0, stream>>>(wobuf, Wo, bo, X, gate, out);
}